// Round 1
// baseline (735.237 us; speedup 1.0000x reference)
//
#include <hip/hip_runtime.h>
#include <math.h>

#define F_IN 256
#define CH   16
#define NL   7

// ---------------------------------------------------------------- degree
__global__ void k_degree(const int* __restrict__ dst, int E, int* __restrict__ deg) {
    int i = blockIdx.x * blockDim.x + threadIdx.x;
    if (i < E) atomicAdd(&deg[dst[i]], 1);
}

// ---------------------------------------------------------------- gemm1: g = (x @ W0) * dinv
// one wave per row; lane = q*16 + c  (q = k-quarter, c = out channel)
__global__ __launch_bounds__(256) void k_gemm1(const float* __restrict__ x,
                                               const float* __restrict__ W0,
                                               const int* __restrict__ deg,
                                               float* __restrict__ g, int N) {
    int lane = threadIdx.x & 63;
    int q = lane >> 4;   // which quarter of K (64 k's each)
    int c = lane & 15;   // output channel
    float w[64];
#pragma unroll
    for (int t = 0; t < 64; ++t) w[t] = W0[(q * 64 + t) * CH + c];

    int wave  = (blockIdx.x * blockDim.x + threadIdx.x) >> 6;
    int nwave = (gridDim.x * blockDim.x) >> 6;
    for (int row = wave; row < N; row += nwave) {
        const float4* xp = (const float4*)(x + row * F_IN + q * 64);
        float acc = 0.f;
#pragma unroll
        for (int t = 0; t < 16; ++t) {
            float4 v = xp[t];
            acc += v.x * w[4*t] + v.y * w[4*t+1] + v.z * w[4*t+2] + v.w * w[4*t+3];
        }
        acc += __shfl_xor(acc, 16);
        acc += __shfl_xor(acc, 32);
        if (q == 0) {
            float dinv = rsqrtf((float)(deg[row] + 1));
            g[row * CH + c] = acc * dinv;
        }
    }
}

// ---------------------------------------------------------------- edge scatter, layer 1 (16 ch)
__global__ void k_edge1(const int* __restrict__ src, const int* __restrict__ dst,
                        const float* __restrict__ g, float* __restrict__ acc, int tot) {
    int tid = blockIdx.x * blockDim.x + threadIdx.x;
    if (tid >= tot) return;
    int e = tid >> 4, c = tid & 15;
    int s = src[e], d = dst[e];
    unsafeAtomicAdd(&acc[d * CH + c], g[s * CH + c]);
}

// ---------------------------------------------------------------- layer2: g2 = relu(dinv*(accA+g)) @ W1 * dinv
// 8 lanes per row (j = channel, padded to 8; j==7 produces 0)
__global__ __launch_bounds__(256) void k_layer2(const float* __restrict__ g,
                                                const float* __restrict__ accA,
                                                const float* __restrict__ W1,
                                                const int* __restrict__ deg,
                                                float* __restrict__ g2, int N) {
    int lane = threadIdx.x & 63;
    int j = lane & 7;
    float w1[CH];
#pragma unroll
    for (int c = 0; c < CH; ++c) w1[c] = (j < NL) ? W1[c * NL + j] : 0.f;

    int grp  = (blockIdx.x * blockDim.x + threadIdx.x) >> 3;
    int ngrp = (gridDim.x * blockDim.x) >> 3;
    for (int row = grp; row < N; row += ngrp) {
        float dinv = rsqrtf((float)(deg[row] + 1));
        const float4* gp = (const float4*)(g + row * CH);
        const float4* ap = (const float4*)(accA + row * CH);
        float h2 = 0.f;
#pragma unroll
        for (int t = 0; t < 4; ++t) {
            float4 gv = gp[t], av = ap[t];
            float h;
            h = fmaxf(dinv * (gv.x + av.x), 0.f); h2 += h * w1[4*t+0];
            h = fmaxf(dinv * (gv.y + av.y), 0.f); h2 += h * w1[4*t+1];
            h = fmaxf(dinv * (gv.z + av.z), 0.f); h2 += h * w1[4*t+2];
            h = fmaxf(dinv * (gv.w + av.w), 0.f); h2 += h * w1[4*t+3];
        }
        g2[row * 8 + j] = h2 * dinv;
    }
}

// ---------------------------------------------------------------- edge scatter, layer 2 (7 ch in 8-stride)
__global__ void k_edge2(const int* __restrict__ src, const int* __restrict__ dst,
                        const float* __restrict__ g2, float* __restrict__ acc, int tot) {
    int tid = blockIdx.x * blockDim.x + threadIdx.x;
    if (tid >= tot) return;
    int e = tid >> 3, j = tid & 7;
    if (j < NL) unsafeAtomicAdd(&acc[dst[e] * 8 + j], g2[src[e] * 8 + j]);
}

// ---------------------------------------------------------------- finalize: out = exp(dinv*(accB+g2)) + 1
__global__ void k_final(const float* __restrict__ g2, const float* __restrict__ accB,
                        const int* __restrict__ deg, float* __restrict__ out, int N) {
    int tid = blockIdx.x * blockDim.x + threadIdx.x;
    int row = tid >> 3, j = tid & 7;
    if (row >= N || j >= NL) return;
    float dinv = rsqrtf((float)(deg[row] + 1));
    out[row * NL + j] = __expf(dinv * (g2[row * 8 + j] + accB[row * 8 + j])) + 1.0f;
}

extern "C" void kernel_launch(void* const* d_in, const int* in_sizes, int n_in,
                              void* d_out, int out_size, void* d_ws, size_t ws_size,
                              hipStream_t stream) {
    const float* x  = (const float*)d_in[0];
    const float* W0 = (const float*)d_in[1];
    const float* W1 = (const float*)d_in[2];
    const int*   ei = (const int*)d_in[3];

    const int N = in_sizes[0] / F_IN;       // 100000
    const int E = in_sizes[3] / 2;          // 3200000
    const int* src = ei;
    const int* dst = ei + E;

    // workspace layout (floats): accA[N*16] | accB[N*8] | deg[N] | g[N*16] | g2[N*8]
    float* accA = (float*)d_ws;
    float* accB = accA + (size_t)N * CH;
    int*   deg  = (int*)(accB + (size_t)N * 8);
    float* g    = (float*)(deg + N);
    float* g2   = g + (size_t)N * CH;

    float* out = (float*)d_out;

    // zero accA + accB + deg in one contiguous memset (N*(16+8+1)*4 bytes)
    hipMemsetAsync(d_ws, 0, (size_t)N * (CH + 8 + 1) * sizeof(float), stream);

    // 1) degree
    k_degree<<<(E + 255) / 256, 256, 0, stream>>>(dst, E, deg);

    // 2) g = (x@W0) * dinv   (memory-bound on x: 102 MB)
    k_gemm1<<<2048, 256, 0, stream>>>(x, W0, deg, g, N);

    // 3) accA[dst] += g[src]   (E*16 fp32 atomics)
    {
        int tot = E * CH;
        k_edge1<<<(tot + 255) / 256, 256, 0, stream>>>(src, dst, g, accA, tot);
    }

    // 4) g2 = relu(dinv*(accA+g)) @ W1 * dinv  (padded to 8 ch)
    k_layer2<<<(N * 8 + 255) / 256, 256, 0, stream>>>(g, accA, W1, deg, g2, N);

    // 5) accB[dst] += g2[src]
    {
        int tot = E * 8;
        k_edge2<<<(tot + 255) / 256, 256, 0, stream>>>(src, dst, g2, accB, tot);
    }

    // 6) out = exp(dinv*(accB+g2)) + 1
    k_final<<<(N * 8 + 255) / 256, 256, 0, stream>>>(g2, accB, deg, out, N);
}